// Round 5
// baseline (364.392 us; speedup 1.0000x reference)
//
#include <hip/hip_runtime.h>

// Sinkhorn divergence (geomloss 'sinkhorn', p=2, blur=0.05, diameter=4, scaling=0.5, debias)
// B=2, N=M=4096, D=3, fp32.
// R5: occupancy 4->8 waves/SIMD (BLOCK 256, COLS 512, launch_bounds(256,8) => VGPR<=64),
// zero-pad LDS region replaces exec-masked reads (lanes>=32 read zeros, stride 0),
// 2-tile/4-MFMA/2-merge8 inner loop sized to fit the 64-VGPR cap.
// MFMA K-slot packing (split-bf16 products + 3-split T against B=1) unchanged (verified R3/R4).

typedef __attribute__((ext_vector_type(8))) short short8;
typedef __attribute__((ext_vector_type(8))) __bf16 bf16x8;
typedef __attribute__((ext_vector_type(4))) float f32x4;
typedef __attribute__((ext_vector_type(2))) float f32x2;

#define NPT 4096
#define BLOCK 256
#define COLS 512            // columns per block (one part)
#define NPARTS 8
#define ROWS_PER_BLOCK 128  // 4 waves x 2 rowsets x 16
#define NRC 32              // rowchunks
#define EXP2 __builtin_amdgcn_exp2f
#define LOG2 __builtin_amdgcn_logf
#define KLOG2E 1.4426950408889634f
#define KLN2 0.6931471805599453f

__device__ inline unsigned short f2bf(float f) {
  unsigned u = __float_as_uint(f);
  return (unsigned short)((u + 0x7FFF + ((u >> 16) & 1)) >> 16);
}
__device__ inline float bf2f(unsigned short h) {
  return __uint_as_float(((unsigned)h) << 16);
}

struct SArgs {
  const float* rowPts[4];
  const float* colPts[4];
  const float2* Pprev;   // partials from previous launch [8 tbl][8 part][4096] (m,s)
  float2* Pcur;
  const float* Fprev;    // finalized potentials [8 tbl][4096]
  float* Fcur;
  float eps, epsPrev;
  int usePot, avgPrev;
};

// merge 8 values (two f32x4) into running (m,s)
__device__ inline void lse_merge8(float& m, float& s, f32x4 a, f32x4 b) {
  float t0 = fmaxf(fmaxf(a.x, a.y), a.z);
  float t1 = fmaxf(fmaxf(a.w, b.x), b.y);
  float t2 = fmaxf(b.z, b.w);
  float cm = fmaxf(fmaxf(t0, t1), t2);
  float mn = fmaxf(m, cm);
  float sc = EXP2(m - mn);                 // m=-inf first iter -> 0
  f32x2 mn2 = {mn, mn};
  f32x2 sa, sb, d;
  d = (f32x2){a.x, a.y} - mn2; sa = (f32x2){EXP2(d.x), EXP2(d.y)};
  d = (f32x2){a.z, a.w} - mn2; sb = (f32x2){EXP2(d.x), EXP2(d.y)};
  d = (f32x2){b.x, b.y} - mn2; sa += (f32x2){EXP2(d.x), EXP2(d.y)};
  d = (f32x2){b.z, b.w} - mn2; sb += (f32x2){EXP2(d.x), EXP2(d.y)};
  sa += sb;
  s = fmaf(s, sc, sa.x + sa.y);
  m = mn;
}

__global__ __launch_bounds__(BLOCK, 8) void softmin_mfma(SArgs A) {
  // frag[0..511]=k0..7 per column, frag[512..1023]=k8..15, frag[1024..1055]=zeros
  __shared__ short8 frag[2 * COLS + 32];

  const int bid  = blockIdx.x;
  const int tbl  = bid >> 8;          // /(NPARTS*NRC)=256 -> 0..7 = task*2+batch
  const int task = tbl >> 1, batch = tbl & 1;
  const int rem  = bid & 255;
  const int part = rem >> 5;          // 0..7
  const int rc   = rem & 31;          // 0..31

  const float* yp = A.colPts[task] + batch * NPT * 3;
  const float* xp = A.rowPts[task] + batch * NPT * 3;

  const float inv_eps = 1.0f / A.eps;
  const float sY = inv_eps * KLOG2E;
  const float hc = -8.317766166719343f;   // -ln(4096)
  const int pidxA[4] = {1, 0, 2, 3};
  const int tP = pidxA[task] * 2 + batch;

  const int lane = threadIdx.x & 63;
  const int wave = threadIdx.x >> 6;
  const int q    = lane >> 4;

  // ---- build B fragments (row side), 2 rowsets of 16 rows per wave ----
  const int rowbase = rc * ROWS_PER_BLOCK + wave * 32;
  bf16x8 Bf[2];
#pragma unroll
  for (int rs = 0; rs < 2; ++rs) {
    int i = rowbase + rs * 16 + (lane & 15);
    float X0 = xp[3 * i], X1 = xp[3 * i + 1], X2 = xp[3 * i + 2];
    unsigned short xh0 = f2bf(X0), xh1 = f2bf(X1), xh2 = f2bf(X2);
    unsigned short xl0 = f2bf(X0 - bf2f(xh0));
    unsigned short xl1 = f2bf(X1 - bf2f(xh1));
    unsigned short xl2 = f2bf(X2 - bf2f(xh2));
    short8 bb = (short8)0;
    if (q == 0) {
      short8 t = {(short)xh0, (short)xh1, (short)xh2,
                  (short)xh0, (short)xh1, (short)xh2,
                  (short)xl0, (short)xl1};
      bb = t;
    } else if (q == 1) {
      short8 t = {(short)xl2, (short)0x3F80, (short)0x3F80, (short)0x3F80,
                  (short)xl0, (short)xl1, (short)xl2, 0};
      bb = t;
    }
    Bf[rs] = __builtin_bit_cast(bf16x8, bb);
  }

  // zero-pad region for lanes >= 32 (reads k16..31 operands as 0)
  if (threadIdx.x < 32) frag[2 * COLS + threadIdx.x] = (short8)0;

  // ---- staging: finalize prev-launch potentials + build column A-fragments ----
  for (int c = 0; c < COLS / BLOCK; ++c) {
    int jl = threadIdx.x + c * BLOCK;
    int j  = part * COLS + jl;
    float y0 = yp[3 * j], y1 = yp[3 * j + 1], y2 = yp[3 * j + 2];
    float y2n = 0.5f * (y0 * y0 + y1 * y1 + y2 * y2);
    float pot = 0.0f;
    if (A.usePot) {
      float M = -__builtin_inff();
      float2 qv[NPARTS];
#pragma unroll
      for (int p = 0; p < NPARTS; ++p) {
        qv[p] = A.Pprev[(tP * NPARTS + p) * NPT + j];
        M = fmaxf(M, qv[p].x);
      }
      float S = 0.0f;
#pragma unroll
      for (int p = 0; p < NPARTS; ++p) S += qv[p].y * EXP2(qv[p].x - M);
      float L = M + LOG2(S);
      float r = y2n - A.epsPrev * KLN2 * L;
      if (A.avgPrev) r = 0.5f * (A.Fprev[tP * NPT + j] + r);
      pot = r;
      if (rc == 0) A.Fcur[tP * NPT + j] = pot;
    }
    float T = (hc + (pot - y2n) * inv_eps) * KLOG2E;
    float s0 = y0 * sY, s1 = y1 * sY, s2 = y2 * sY;
    unsigned short yh0 = f2bf(s0), yh1 = f2bf(s1), yh2 = f2bf(s2);
    unsigned short yl0 = f2bf(s0 - bf2f(yh0));
    unsigned short yl1 = f2bf(s1 - bf2f(yh1));
    unsigned short yl2 = f2bf(s2 - bf2f(yh2));
    unsigned short Th = f2bf(T);
    float tr = T - bf2f(Th);
    unsigned short Tm = f2bf(tr);
    tr -= bf2f(Tm);
    unsigned short Tl = f2bf(tr);
    short8 h0 = {(short)yh0, (short)yh1, (short)yh2,
                 (short)yl0, (short)yl1, (short)yl2,
                 (short)yh0, (short)yh1};
    short8 h1 = {(short)yh2, (short)Th, (short)Tm, (short)Tl,
                 (short)yl0, (short)yl1, (short)yl2, 0};
    frag[jl] = h0;
    frag[COLS + jl] = h1;
  }
  __syncthreads();

  // ---- inner loop: 2 column tiles (32 cols) per iteration, 4 MFMAs ----
  // per-lane base: q0 -> frag[0..], q1 -> frag[512..], q>=2 -> zero pad; stride 0 for q>=2
  int idx = ((q == 0) ? 0 : (q == 1) ? COLS : 2 * COLS) + (lane & 15);
  const int stride = (lane < 32) ? 32 : 0;
  float m0 = -__builtin_inff(), s0_ = 0.0f;
  float m1 = -__builtin_inff(), s1_ = 0.0f;

#pragma unroll 4
  for (int jt = 0; jt < COLS / 32; ++jt) {
    short8 as0 = frag[idx];
    short8 as1 = frag[idx + 16];
    idx += stride;
    bf16x8 A0 = __builtin_bit_cast(bf16x8, as0);
    bf16x8 A1 = __builtin_bit_cast(bf16x8, as1);
    const f32x4 Z = {0.0f, 0.0f, 0.0f, 0.0f};
    f32x4 c00 = __builtin_amdgcn_mfma_f32_16x16x32_bf16(A0, Bf[0], Z, 0, 0, 0);
    f32x4 c01 = __builtin_amdgcn_mfma_f32_16x16x32_bf16(A1, Bf[0], Z, 0, 0, 0);
    f32x4 c10 = __builtin_amdgcn_mfma_f32_16x16x32_bf16(A0, Bf[1], Z, 0, 0, 0);
    f32x4 c11 = __builtin_amdgcn_mfma_f32_16x16x32_bf16(A1, Bf[1], Z, 0, 0, 0);
    lse_merge8(m0, s0_, c00, c01);
    lse_merge8(m1, s1_, c10, c11);
  }

  // ---- cross-quad merge (lanes sharing same row i: xor 16, xor 32) + store partial ----
#pragma unroll
  for (int rs = 0; rs < 2; ++rs) {
    float m = rs ? m1 : m0;
    float s = rs ? s1_ : s0_;
#pragma unroll
    for (int off = 16; off <= 32; off <<= 1) {
      float mo = __shfl_xor(m, off, 64);
      float so = __shfl_xor(s, off, 64);
      float mn = fmaxf(m, mo);
      s = s * EXP2(m - mn) + so * EXP2(mo - mn);
      m = mn;
    }
    if (lane < 16) {
      int i = rowbase + rs * 16 + lane;
      A.Pcur[(tbl * NPARTS + part) * NPT + i] = make_float2(m, s);
    }
  }
}

// reduce1: finalize last-launch partials, per-row contribution, per-block partial sums
__global__ __launch_bounds__(256) void reduce1(const float2* P, float* R1) {
  int u = blockIdx.x * 256 + threadIdx.x;   // 0..8191
  int b = u >> 12, i = u & 4095;
  float Ls[4];
#pragma unroll
  for (int t = 0; t < 4; ++t) {
    int tbl = t * 2 + b;
    float M = -__builtin_inff();
    float2 qv[NPARTS];
#pragma unroll
    for (int p = 0; p < NPARTS; ++p) {
      qv[p] = P[(tbl * NPARTS + p) * NPT + i];
      M = fmaxf(M, qv[p].x);
    }
    float S = 0.0f;
#pragma unroll
    for (int p = 0; p < NPARTS; ++p) S += qv[p].y * EXP2(qv[p].x - M);
    Ls[t] = M + LOG2(S);
  }
  // (b_x - a_x) + (a_y - b_y) = -eps*ln2*((L0 - L2) + (L1 - L3))
  float acc = (Ls[0] - Ls[2]) + (Ls[1] - Ls[3]);
#pragma unroll
  for (int off = 32; off >= 1; off >>= 1) acc += __shfl_xor(acc, off, 64);
  __shared__ float red[4];
  int wave = threadIdx.x >> 6, lane = threadIdx.x & 63;
  if (lane == 0) red[wave] = acc;
  __syncthreads();
  if (threadIdx.x == 0)
    R1[blockIdx.x] = red[0] + red[1] + red[2] + red[3];
}

__global__ __launch_bounds__(64) void reduce2(const float* R1, float* out) {
  float a = (threadIdx.x < 32) ? R1[threadIdx.x] : 0.0f;
#pragma unroll
  for (int off = 32; off >= 1; off >>= 1) a += __shfl_xor(a, off, 64);
  if (threadIdx.x == 0)
    out[0] = a * (-0.0025f * KLN2 / 4096.0f);
}

extern "C" void kernel_launch(void* const* d_in, const int* in_sizes, int n_in,
                              void* d_out, int out_size, void* d_ws, size_t ws_size,
                              hipStream_t stream) {
  const float* x = (const float*)d_in[0];   // true_data
  const float* y = (const float*)d_in[1];   // particles
  float* out = (float*)d_out;
  float* W = (float*)d_ws;

  // partials: 8 tbl x 8 parts x 4096 x float2 = 2 MB per set
  float2* P[2] = { (float2*)W, (float2*)(W + 524288) };
  float*  F[2] = { W + 1048576, W + 1048576 + 32768 };      // 2 x 128 KB finalized pots
  float*  R1buf = W + 1048576 + 65536;                      // 32 floats

  // launch schedule: L0 init; L1..9 loop (eps_list); L10 final extrapolation
  static const float epsL[11] = {16.0f, 16.0f, 16.0f, 4.0f, 1.0f, 0.25f, 0.0625f,
                                 0.015625f, 0.00390625f, 0.0025f, 0.0025f};
  static const int avgL[11] = {0, 1, 1, 1, 1, 1, 1, 1, 1, 1, 0};

  const float* rows[4] = { x, y, x, y };   // b_x<-C_xy, a_y<-C_yx, a_x<-C_xx, b_y<-C_yy
  const float* cols[4] = { y, x, x, y };

  dim3 grid(8 * NPARTS * NRC), block(BLOCK);
  for (int L = 0; L <= 10; ++L) {
    SArgs A;
    for (int t = 0; t < 4; ++t) { A.rowPts[t] = rows[t]; A.colPts[t] = cols[t]; }
    A.Pprev = P[(L + 1) & 1];
    A.Pcur  = P[L & 1];
    A.Fprev = F[(L + 1) & 1];
    A.Fcur  = F[L & 1];
    A.eps = epsL[L];
    A.epsPrev = (L > 0) ? epsL[L - 1] : 1.0f;
    A.usePot = (L > 0) ? 1 : 0;
    A.avgPrev = (L > 0) ? avgL[L - 1] : 0;
    softmin_mfma<<<grid, block, 0, stream>>>(A);
  }
  reduce1<<<32, 256, 0, stream>>>(P[0], R1buf);   // L=10 wrote P[10&1]=P[0]
  reduce2<<<1, 64, 0, stream>>>(R1buf, out);
}

// Round 6
// 329.200 us; speedup vs baseline: 1.1069x; 1.1069x over previous
//
#include <hip/hip_runtime.h>

// Sinkhorn divergence (geomloss 'sinkhorn', p=2, blur=0.05, diameter=4, scaling=0.5, debias)
// B=2, N=M=4096, D=3, fp32.
// R6: 32 waves/CU WITHOUT extra staging: grid stays 512 (COLS 1024, NPARTS 4) but
// BLOCK 1024 (16 waves) x 2 blocks/CU; launch_bounds(1024,8) -> VGPR<=64 -> 8 waves/SIMD.
// Inner loop: 1 rowset/wave, 4 col-tiles + 4 MFMAs + packed merge16 per iter (~52 VGPRs).
// Packed v_pk_max_f32 trees via __builtin_elementwise_max; zero-pad LDS (64 entries) for
// unguarded uniform ds_reads. MFMA K-slot packing unchanged (verified R3-R5, absmax 0).

typedef __attribute__((ext_vector_type(8))) short short8;
typedef __attribute__((ext_vector_type(8))) __bf16 bf16x8;
typedef __attribute__((ext_vector_type(4))) float f32x4;
typedef __attribute__((ext_vector_type(2))) float f32x2;

#define NPT 4096
#define BLOCK 1024
#define COLS 1024           // columns per block (one part)
#define NPARTS 4
#define ROWS_PER_BLOCK 256  // 16 waves x 1 rowset x 16
#define NRC 16              // rowchunks
#define EXP2 __builtin_amdgcn_exp2f
#define LOG2 __builtin_amdgcn_logf
#define KLOG2E 1.4426950408889634f
#define KLN2 0.6931471805599453f

__device__ inline unsigned short f2bf(float f) {
  unsigned u = __float_as_uint(f);
  return (unsigned short)((u + 0x7FFF + ((u >> 16) & 1)) >> 16);
}
__device__ inline float bf2f(unsigned short h) {
  return __uint_as_float(((unsigned)h) << 16);
}

struct SArgs {
  const float* rowPts[4];
  const float* colPts[4];
  const float2* Pprev;   // partials from previous launch [8 tbl][4 part][4096] (m,s)
  float2* Pcur;
  const float* Fprev;    // finalized potentials [8 tbl][4096]
  float* Fcur;
  float eps, epsPrev;
  int usePot, avgPrev;
};

// merge 16 values into running (m,s): packed max tree + packed sub/sum, 16 exp2
__device__ inline void lse_merge16(float& m, float& s,
                                   f32x4 c0, f32x4 c1, f32x4 c2, f32x4 c3) {
  f32x2 p0 = {c0.x, c0.y}, p1 = {c0.z, c0.w};
  f32x2 p2 = {c1.x, c1.y}, p3 = {c1.z, c1.w};
  f32x2 p4 = {c2.x, c2.y}, p5 = {c2.z, c2.w};
  f32x2 p6 = {c3.x, c3.y}, p7 = {c3.z, c3.w};
  f32x2 q0 = __builtin_elementwise_max(p0, p1);
  f32x2 q1 = __builtin_elementwise_max(p2, p3);
  f32x2 q2 = __builtin_elementwise_max(p4, p5);
  f32x2 q3 = __builtin_elementwise_max(p6, p7);
  f32x2 r0 = __builtin_elementwise_max(q0, q1);
  f32x2 r1 = __builtin_elementwise_max(q2, q3);
  f32x2 rm = __builtin_elementwise_max(r0, r1);
  float cm = fmaxf(rm.x, rm.y);
  float mn = fmaxf(m, cm);
  float sc = EXP2(m - mn);                 // m=-inf first iter -> 0
  f32x2 mn2 = {mn, mn};
  f32x2 sa, sb, d;
  d = p0 - mn2; sa  = (f32x2){EXP2(d.x), EXP2(d.y)};
  d = p1 - mn2; sb  = (f32x2){EXP2(d.x), EXP2(d.y)};
  d = p2 - mn2; sa += (f32x2){EXP2(d.x), EXP2(d.y)};
  d = p3 - mn2; sb += (f32x2){EXP2(d.x), EXP2(d.y)};
  d = p4 - mn2; sa += (f32x2){EXP2(d.x), EXP2(d.y)};
  d = p5 - mn2; sb += (f32x2){EXP2(d.x), EXP2(d.y)};
  d = p6 - mn2; sa += (f32x2){EXP2(d.x), EXP2(d.y)};
  d = p7 - mn2; sb += (f32x2){EXP2(d.x), EXP2(d.y)};
  sa += sb;
  s = fmaf(s, sc, sa.x + sa.y);
  m = mn;
}

__global__ __launch_bounds__(BLOCK, 8) void softmin_mfma(SArgs A) {
  // frag[0..1023]=k0..7 per column, frag[1024..2047]=k8..15, frag[2048..2111]=zeros
  __shared__ short8 frag[2 * COLS + 64];

  const int bid  = blockIdx.x;
  const int tbl  = bid >> 6;          // /(NPARTS*NRC)=64 -> 0..7 = task*2+batch
  const int task = tbl >> 1, batch = tbl & 1;
  const int rem  = bid & 63;
  const int part = rem >> 4;          // 0..3
  const int rc   = rem & 15;          // 0..15

  const float* yp = A.colPts[task] + batch * NPT * 3;
  const float* xp = A.rowPts[task] + batch * NPT * 3;

  const float inv_eps = 1.0f / A.eps;
  const float sY = inv_eps * KLOG2E;
  const float hc = -8.317766166719343f;   // -ln(4096)
  const int pidxA[4] = {1, 0, 2, 3};
  const int tP = pidxA[task] * 2 + batch;

  const int lane = threadIdx.x & 63;
  const int wave = threadIdx.x >> 6;  // 0..15
  const int q    = lane >> 4;

  // ---- build B fragment (row side), one rowset of 16 rows per wave ----
  const int rowbase = rc * ROWS_PER_BLOCK + wave * 16;
  bf16x8 Bf;
  {
    int i = rowbase + (lane & 15);
    float X0 = xp[3 * i], X1 = xp[3 * i + 1], X2 = xp[3 * i + 2];
    unsigned short xh0 = f2bf(X0), xh1 = f2bf(X1), xh2 = f2bf(X2);
    unsigned short xl0 = f2bf(X0 - bf2f(xh0));
    unsigned short xl1 = f2bf(X1 - bf2f(xh1));
    unsigned short xl2 = f2bf(X2 - bf2f(xh2));
    short8 bb = (short8)0;
    if (q == 0) {
      short8 t = {(short)xh0, (short)xh1, (short)xh2,
                  (short)xh0, (short)xh1, (short)xh2,
                  (short)xl0, (short)xl1};
      bb = t;
    } else if (q == 1) {
      short8 t = {(short)xl2, (short)0x3F80, (short)0x3F80, (short)0x3F80,
                  (short)xl0, (short)xl1, (short)xl2, 0};
      bb = t;
    }
    Bf = __builtin_bit_cast(bf16x8, bb);
  }

  // zero-pad region for lanes >= 32 (reads k16..31 operands as 0); 64 entries
  if (threadIdx.x < 64) frag[2 * COLS + threadIdx.x] = (short8)0;

  // ---- staging: finalize prev-launch potentials + build column A-fragments ----
  {
    int jl = threadIdx.x;             // COLS == BLOCK
    int j  = part * COLS + jl;
    float y0 = yp[3 * j], y1 = yp[3 * j + 1], y2 = yp[3 * j + 2];
    float y2n = 0.5f * (y0 * y0 + y1 * y1 + y2 * y2);
    float pot = 0.0f;
    if (A.usePot) {
      float2 q0 = A.Pprev[(tP * NPARTS + 0) * NPT + j];
      float2 q1 = A.Pprev[(tP * NPARTS + 1) * NPT + j];
      float2 q2 = A.Pprev[(tP * NPARTS + 2) * NPT + j];
      float2 q3 = A.Pprev[(tP * NPARTS + 3) * NPT + j];
      float M = fmaxf(fmaxf(q0.x, q1.x), fmaxf(q2.x, q3.x));
      float S = q0.y * EXP2(q0.x - M) + q1.y * EXP2(q1.x - M)
              + q2.y * EXP2(q2.x - M) + q3.y * EXP2(q3.x - M);
      float L = M + LOG2(S);
      float r = y2n - A.epsPrev * KLN2 * L;
      if (A.avgPrev) r = 0.5f * (A.Fprev[tP * NPT + j] + r);
      pot = r;
      if (rc == 0) A.Fcur[tP * NPT + j] = pot;
    }
    float T = (hc + (pot - y2n) * inv_eps) * KLOG2E;
    float s0 = y0 * sY, s1 = y1 * sY, s2 = y2 * sY;
    unsigned short yh0 = f2bf(s0), yh1 = f2bf(s1), yh2 = f2bf(s2);
    unsigned short yl0 = f2bf(s0 - bf2f(yh0));
    unsigned short yl1 = f2bf(s1 - bf2f(yh1));
    unsigned short yl2 = f2bf(s2 - bf2f(yh2));
    unsigned short Th = f2bf(T);
    float tr = T - bf2f(Th);
    unsigned short Tm = f2bf(tr);
    tr -= bf2f(Tm);
    unsigned short Tl = f2bf(tr);
    short8 h0 = {(short)yh0, (short)yh1, (short)yh2,
                 (short)yl0, (short)yl1, (short)yl2,
                 (short)yh0, (short)yh1};
    short8 h1 = {(short)yh2, (short)Th, (short)Tm, (short)Tl,
                 (short)yl0, (short)yl1, (short)yl2, 0};
    frag[jl] = h0;
    frag[COLS + jl] = h1;
  }
  __syncthreads();

  // ---- inner loop: 4 column tiles (64 cols) per iteration, 4 MFMAs, 1 merge16 ----
  // per-lane base: q0 -> frag[0..], q1 -> frag[COLS..], q>=2 -> zero pad (stride 0)
  int idx = ((q == 0) ? 0 : (q == 1) ? COLS : 2 * COLS) + (lane & 15);
  const int stride = (lane < 32) ? 64 : 0;
  float m0 = -__builtin_inff(), s0_ = 0.0f;

#pragma unroll 2
  for (int jt = 0; jt < COLS / 64; ++jt) {
    short8 as0 = frag[idx];
    short8 as1 = frag[idx + 16];
    short8 as2 = frag[idx + 32];
    short8 as3 = frag[idx + 48];
    idx += stride;
    bf16x8 A0 = __builtin_bit_cast(bf16x8, as0);
    bf16x8 A1 = __builtin_bit_cast(bf16x8, as1);
    bf16x8 A2 = __builtin_bit_cast(bf16x8, as2);
    bf16x8 A3 = __builtin_bit_cast(bf16x8, as3);
    const f32x4 Z = {0.0f, 0.0f, 0.0f, 0.0f};
    f32x4 c0 = __builtin_amdgcn_mfma_f32_16x16x32_bf16(A0, Bf, Z, 0, 0, 0);
    f32x4 c1 = __builtin_amdgcn_mfma_f32_16x16x32_bf16(A1, Bf, Z, 0, 0, 0);
    f32x4 c2 = __builtin_amdgcn_mfma_f32_16x16x32_bf16(A2, Bf, Z, 0, 0, 0);
    f32x4 c3 = __builtin_amdgcn_mfma_f32_16x16x32_bf16(A3, Bf, Z, 0, 0, 0);
    lse_merge16(m0, s0_, c0, c1, c2, c3);
  }

  // ---- cross-quad merge (lanes sharing same row i: xor 16, xor 32) + store partial ----
  {
    float m = m0, s = s0_;
#pragma unroll
    for (int off = 16; off <= 32; off <<= 1) {
      float mo = __shfl_xor(m, off, 64);
      float so = __shfl_xor(s, off, 64);
      float mn = fmaxf(m, mo);
      s = s * EXP2(m - mn) + so * EXP2(mo - mn);
      m = mn;
    }
    if (lane < 16) {
      int i = rowbase + lane;
      A.Pcur[(tbl * NPARTS + part) * NPT + i] = make_float2(m, s);
    }
  }
}

// reduce1: finalize last-launch partials, per-row contribution, per-block partial sums
__global__ __launch_bounds__(256) void reduce1(const float2* P, float* R1) {
  int u = blockIdx.x * 256 + threadIdx.x;   // 0..8191
  int b = u >> 12, i = u & 4095;
  float Ls[4];
#pragma unroll
  for (int t = 0; t < 4; ++t) {
    int tbl = t * 2 + b;
    float2 q0 = P[(tbl * NPARTS + 0) * NPT + i];
    float2 q1 = P[(tbl * NPARTS + 1) * NPT + i];
    float2 q2 = P[(tbl * NPARTS + 2) * NPT + i];
    float2 q3 = P[(tbl * NPARTS + 3) * NPT + i];
    float M = fmaxf(fmaxf(q0.x, q1.x), fmaxf(q2.x, q3.x));
    float S = q0.y * EXP2(q0.x - M) + q1.y * EXP2(q1.x - M)
            + q2.y * EXP2(q2.x - M) + q3.y * EXP2(q3.x - M);
    Ls[t] = M + LOG2(S);
  }
  // (b_x - a_x) + (a_y - b_y) = -eps*ln2*((L0 - L2) + (L1 - L3))
  float acc = (Ls[0] - Ls[2]) + (Ls[1] - Ls[3]);
#pragma unroll
  for (int off = 32; off >= 1; off >>= 1) acc += __shfl_xor(acc, off, 64);
  __shared__ float red[4];
  int wave = threadIdx.x >> 6, lane = threadIdx.x & 63;
  if (lane == 0) red[wave] = acc;
  __syncthreads();
  if (threadIdx.x == 0)
    R1[blockIdx.x] = red[0] + red[1] + red[2] + red[3];
}

__global__ __launch_bounds__(64) void reduce2(const float* R1, float* out) {
  float a = (threadIdx.x < 32) ? R1[threadIdx.x] : 0.0f;
#pragma unroll
  for (int off = 32; off >= 1; off >>= 1) a += __shfl_xor(a, off, 64);
  if (threadIdx.x == 0)
    out[0] = a * (-0.0025f * KLN2 / 4096.0f);
}

extern "C" void kernel_launch(void* const* d_in, const int* in_sizes, int n_in,
                              void* d_out, int out_size, void* d_ws, size_t ws_size,
                              hipStream_t stream) {
  const float* x = (const float*)d_in[0];   // true_data
  const float* y = (const float*)d_in[1];   // particles
  float* out = (float*)d_out;
  float* W = (float*)d_ws;

  // partials: 8 tbl x 4 parts x 4096 x float2 = 1 MB per set
  float2* P[2] = { (float2*)W, (float2*)(W + 262144) };
  float*  F[2] = { W + 524288, W + 557056 };      // 2 x 128 KB finalized pots
  float*  R1buf = W + 589824;                     // 32 floats

  // launch schedule: L0 init; L1..9 loop (eps_list); L10 final extrapolation
  static const float epsL[11] = {16.0f, 16.0f, 16.0f, 4.0f, 1.0f, 0.25f, 0.0625f,
                                 0.015625f, 0.00390625f, 0.0025f, 0.0025f};
  static const int avgL[11] = {0, 1, 1, 1, 1, 1, 1, 1, 1, 1, 0};

  const float* rows[4] = { x, y, x, y };   // b_x<-C_xy, a_y<-C_yx, a_x<-C_xx, b_y<-C_yy
  const float* cols[4] = { y, x, x, y };

  dim3 grid(8 * NPARTS * NRC), block(BLOCK);
  for (int L = 0; L <= 10; ++L) {
    SArgs A;
    for (int t = 0; t < 4; ++t) { A.rowPts[t] = rows[t]; A.colPts[t] = cols[t]; }
    A.Pprev = P[(L + 1) & 1];
    A.Pcur  = P[L & 1];
    A.Fprev = F[(L + 1) & 1];
    A.Fcur  = F[L & 1];
    A.eps = epsL[L];
    A.epsPrev = (L > 0) ? epsL[L - 1] : 1.0f;
    A.usePot = (L > 0) ? 1 : 0;
    A.avgPrev = (L > 0) ? avgL[L - 1] : 0;
    softmin_mfma<<<grid, block, 0, stream>>>(A);
  }
  reduce1<<<32, 256, 0, stream>>>(P[0], R1buf);   // L=10 wrote P[10&1]=P[0]
  reduce2<<<1, 64, 0, stream>>>(R1buf, out);
}